// Round 10
// baseline (13331.548 us; speedup 1.0000x reference)
//
#include <hip/hip_runtime.h>

#define HH 512
#define OO 256
#define BB 64
#define SS 1024
#define TT 256
#define KK 1280   // H(ctx) + O(target) + H(h)

typedef __attribute__((ext_vector_type(8))) short bh8;
typedef __attribute__((ext_vector_type(8))) _Float16 hf8;
typedef __attribute__((ext_vector_type(4))) float fx4;

__device__ __forceinline__ unsigned short f2bf(float x) {
    union { float f; unsigned int u; } v; v.f = x;
    unsigned int r = v.u + 0x7fffu + ((v.u >> 16) & 1u);
    return (unsigned short)(r >> 16);
}
__device__ __forceinline__ float bf2f(unsigned short s) {
    union { unsigned int u; float f; } z; z.u = ((unsigned int)s) << 16; return z.f;
}

// Pack W_cat = [W_ih | W_hh] (j-permuted; see round-0 comment) into MFMA
// B-fragment-major bf16 hi/lo split: W = hi + lo, lo = bf16(W - f32(hi)).
__global__ void prep_weights(const float* __restrict__ W_ih,
                             const float* __restrict__ W_hh,
                             unsigned short* __restrict__ wfH,
                             unsigned short* __restrict__ wfL) {
    int g = blockIdx.x * 256 + threadIdx.x;     // 64*40*2*64 = 327680 groups
    if (g >= 64 * 40 * 2 * 64) return;
    int lane = g & 63;
    int nt = (g >> 6) & 1;
    int kk = (g >> 7) % 40;
    int ht = (g >> 7) / 40;
    int c = nt * 16 + (lane & 15);
    int gate = c >> 3, rr = c & 7;
    int j = gate * 512 + ht * 8 + rr;
    int kbase = kk * 32 + (lane >> 4) * 8;
    unsigned short* dh = wfH + (size_t)g * 8;
    unsigned short* dl = wfL + (size_t)g * 8;
#pragma unroll
    for (int r = 0; r < 8; ++r) {
        int k = kbase + r;
        float v = (k < 768) ? W_ih[(size_t)j * 768 + k]
                            : W_hh[(size_t)j * 512 + (k - 768)];
        unsigned short hi = f2bf(v);
        dh[r] = hi;
        dl[r] = f2bf(v - bf2f(hi));
    }
}

__global__ void prep_misc(const float* __restrict__ hidden,
                          const float* __restrict__ cell,
                          float* __restrict__ h, float* __restrict__ c) {
    const int total = 32768 + 32768;
    for (int i = blockIdx.x * 256 + threadIdx.x; i < total; i += gridDim.x * 256) {
        if (i < 32768) h[i] = hidden[i];
        else           c[i - 32768] = cell[i - 32768];
    }
}

// One-time fp32 -> fp16 convert of encoder_outputs (33.5M elems, 8/thread).
__global__ void prep_enc(const float* __restrict__ enc,
                         _Float16* __restrict__ ench) {
    const size_t i = ((size_t)blockIdx.x * 256 + threadIdx.x) * 8;
    const float4 a = *(const float4*)(enc + i);
    const float4 b = *(const float4*)(enc + i + 4);
    hf8 o;
    o[0] = (_Float16)a.x; o[1] = (_Float16)a.y;
    o[2] = (_Float16)a.z; o[3] = (_Float16)a.w;
    o[4] = (_Float16)b.x; o[5] = (_Float16)b.y;
    o[6] = (_Float16)b.z; o[7] = (_Float16)b.w;
    *(hf8*)(ench + i) = o;
}

// One dispatch: blocks 0..63 = full attention for batch b (16 waves x 64 rows,
// in-block softmax combine via LDS) -> xb hi/lo. Blocks 64..127 = FC(t-1).
// Fence-free; visibility via kernel boundaries.
__global__ void __launch_bounds__(1024)
step_attnx(int t, const _Float16* __restrict__ ench,
           const float* __restrict__ h, const float* __restrict__ target,
           unsigned short* __restrict__ xbh, unsigned short* __restrict__ xbl,
           const float* __restrict__ W_fc, const float* __restrict__ b_fc,
           float* __restrict__ out) {
    const int tid = threadIdx.x;
    const int lane = tid & 63;
    const int w = tid >> 6;          // wave 0..15

    __shared__ union {
        struct { float m[16]; float l[16]; float ctx[16][512]; } a;  // 33 KB
        struct { float acc[256][4]; } o;                             // 4 KB
    } sh;

    const int bid = blockIdx.x;
    if (bid < 64) {
        const int b = bid;
        const float* hb = h + b * HH + lane * 8;
        const float4 h0 = *(const float4*)hb;
        const float4 h1 = *(const float4*)(hb + 4);
        float m = -3.0e38f, l = 0.f;
        float cx[8];
#pragma unroll
        for (int j = 0; j < 8; ++j) cx[j] = 0.f;
        // wave w owns rows w*64 .. w*64+63, processed in 32 row-pairs
        const _Float16* er = ench + ((size_t)(b * SS + w * 64)) * HH + lane * 8;
        for (int rp = 0; rp < 32; ++rp) {
            const hf8 ev = *(const hf8*)er;
            const hf8 fv = *(const hf8*)(er + HH);
            float e[8], f[8];
#pragma unroll
            for (int j = 0; j < 8; ++j) {
                e[j] = (float)ev[j];
                f[j] = (float)fv[j];
            }
            float dA = e[0]*h0.x + e[1]*h0.y + e[2]*h0.z + e[3]*h0.w
                     + e[4]*h1.x + e[5]*h1.y + e[6]*h1.z + e[7]*h1.w;
            float dB = f[0]*h0.x + f[1]*h0.y + f[2]*h0.z + f[3]*h0.w
                     + f[4]*h1.x + f[5]*h1.y + f[6]*h1.z + f[7]*h1.w;
#pragma unroll
            for (int off = 32; off; off >>= 1) {
                dA += __shfl_xor(dA, off);
                dB += __shfl_xor(dB, off);
            }
            const float mx = fmaxf(dA, dB);
            if (mx > m) {                      // wave-uniform branch
                const float fs = __expf(m - mx);
                l *= fs;
#pragma unroll
                for (int j = 0; j < 8; ++j) cx[j] *= fs;
                m = mx;
            }
            const float pA = __expf(dA - m);
            const float pB = __expf(dB - m);
            l += pA + pB;
#pragma unroll
            for (int j = 0; j < 8; ++j) cx[j] += pA * e[j] + pB * f[j];
            er += 2 * HH;
        }
        if (lane == 0) { sh.a.m[w] = m; sh.a.l[w] = l; }
        *(float4*)&sh.a.ctx[w][lane * 8]     = make_float4(cx[0], cx[1], cx[2], cx[3]);
        *(float4*)&sh.a.ctx[w][lane * 8 + 4] = make_float4(cx[4], cx[5], cx[6], cx[7]);
        __syncthreads();
        // in-block combine of the 16 wave partials
        float M = -3.0e38f;
#pragma unroll
        for (int q = 0; q < 16; ++q) M = fmaxf(M, sh.a.m[q]);
        float wq[16]; float lsb = 0.f;
#pragma unroll
        for (int q = 0; q < 16; ++q) {
            wq[q] = __expf(sh.a.m[q] - M);
            lsb += wq[q] * sh.a.l[q];
        }
        const float inv = 1.0f / lsb;
        if (tid < 512) {
            float s = 0.f;
#pragma unroll
            for (int q = 0; q < 16; ++q) s += wq[q] * sh.a.ctx[q][tid];
            s *= inv;
            const unsigned short a0 = f2bf(s);
            xbh[b * KK + tid] = a0;
            xbl[b * KK + tid] = f2bf(s - bf2f(a0));
        } else if (tid < 768) {
            const int o = tid - 512;
            const float tv = target[((size_t)b * TT + t) * OO + o];
            const unsigned short t0 = f2bf(tv);
            xbh[b * KK + 512 + o] = t0;
            xbl[b * KK + 512 + o] = f2bf(tv - bf2f(t0));
        } else {
            const int h2 = (tid - 768) * 2;
            const float hv0 = h[b * HH + h2], hv1 = h[b * HH + h2 + 1];
            const unsigned short g0 = f2bf(hv0), g1 = f2bf(hv1);
            xbh[b * KK + 768 + h2]     = g0;
            xbl[b * KK + 768 + h2]     = f2bf(hv0 - bf2f(g0));
            xbh[b * KK + 768 + h2 + 1] = g1;
            xbl[b * KK + 768 + h2 + 1] = f2bf(hv1 - bf2f(g1));
        }
    } else if (t > 0) {
        // FC for out[t-1], batch b = bid-64: 256 outputs x 4-way K split
        const int b = bid - 64;
        const int o = tid & 255, kq = tid >> 8;
        float acc = 0.f;
        const float* hp = h + b * HH + kq * 128;
        const float* wp = W_fc + (size_t)o * HH + kq * 128;
#pragma unroll 8
        for (int k2 = 0; k2 < 128; ++k2) acc += hp[k2] * wp[k2];
        sh.o.acc[o][kq] = acc;
        __syncthreads();
        if (tid < 256) {
            float vv = sh.o.acc[tid][0] + sh.o.acc[tid][1]
                     + sh.o.acc[tid][2] + sh.o.acc[tid][3] + b_fc[tid];
            out[((size_t)b * TT + (t - 1)) * OO + tid] = vv;
        }
    }
}

// One block per h-tile: split-bf16 gates GEMM (xh*Wh + xl*Wh + xh*Wl) + cell.
__global__ void __launch_bounds__(256)
step_gates(const unsigned short* __restrict__ xbh,
           const unsigned short* __restrict__ xbl,
           const unsigned short* __restrict__ wfH,
           const unsigned short* __restrict__ wfL,
           const float* __restrict__ b_ih, const float* __restrict__ b_hh,
           float* __restrict__ h, float* __restrict__ c) {
    const int tid = threadIdx.x;
    const int lane = tid & 63;
    const int w = tid >> 6;
    __shared__ float g[64][32];

    const int ht = blockIdx.x;
    fx4 a0 = {0, 0, 0, 0}, a1 = {0, 0, 0, 0};
    const int bro = 16 * w + (lane & 15);
    const int kg = lane >> 4;
    const size_t wbase = (size_t)ht * 40 * 2 * 512;
    for (int kk = 0; kk < 40; ++kk) {
        const size_t aoff = (size_t)bro * KK + kk * 32 + kg * 8;
        bh8 avh = *(const bh8*)(xbh + aoff);
        bh8 avl = *(const bh8*)(xbl + aoff);
        bh8 b0h = *(const bh8*)(wfH + wbase + (kk * 2 + 0) * 512 + lane * 8);
        bh8 b1h = *(const bh8*)(wfH + wbase + (kk * 2 + 1) * 512 + lane * 8);
        bh8 b0l = *(const bh8*)(wfL + wbase + (kk * 2 + 0) * 512 + lane * 8);
        bh8 b1l = *(const bh8*)(wfL + wbase + (kk * 2 + 1) * 512 + lane * 8);
        a0 = __builtin_amdgcn_mfma_f32_16x16x32_bf16(avh, b0h, a0, 0, 0, 0);
        a0 = __builtin_amdgcn_mfma_f32_16x16x32_bf16(avl, b0h, a0, 0, 0, 0);
        a0 = __builtin_amdgcn_mfma_f32_16x16x32_bf16(avh, b0l, a0, 0, 0, 0);
        a1 = __builtin_amdgcn_mfma_f32_16x16x32_bf16(avh, b1h, a1, 0, 0, 0);
        a1 = __builtin_amdgcn_mfma_f32_16x16x32_bf16(avl, b1h, a1, 0, 0, 0);
        a1 = __builtin_amdgcn_mfma_f32_16x16x32_bf16(avh, b1l, a1, 0, 0, 0);
    }
    const int crow = (lane >> 4) * 4;
#pragma unroll
    for (int r = 0; r < 4; ++r) {
        g[16 * w + crow + r][lane & 15]        = a0[r];
        g[16 * w + crow + r][16 + (lane & 15)] = a1[r];
    }
    __syncthreads();
#pragma unroll
    for (int p = 0; p < 2; ++p) {
        const int idx = tid * 2 + p;
        const int b = idx >> 3, r = idx & 7;
        const int hidx = ht * 8 + r;
        float gi = g[b][r]      + b_ih[hidx]        + b_hh[hidx];
        float gf = g[b][8 + r]  + b_ih[512 + hidx]  + b_hh[512 + hidx];
        float gg = g[b][16 + r] + b_ih[1024 + hidx] + b_hh[1024 + hidx];
        float go = g[b][24 + r] + b_ih[1536 + hidx] + b_hh[1536 + hidx];
        float ig = 1.f / (1.f + __expf(-gi));
        float fg = 1.f / (1.f + __expf(-gf));
        float g2 = tanhf(gg);
        float og = 1.f / (1.f + __expf(-go));
        float cn = fg * c[b * HH + hidx] + ig * g2;
        float hn = og * tanhf(cn);
        c[b * HH + hidx] = cn;
        h[b * HH + hidx] = hn;
    }
}

// Final FC: out[TT-1] from final h. 64 blocks x 1024 threads (same math).
__global__ void __launch_bounds__(1024)
fc_final(const float* __restrict__ h, const float* __restrict__ W_fc,
         const float* __restrict__ b_fc, float* __restrict__ out) {
    __shared__ float acc[256][4];
    const int tid = threadIdx.x;
    const int b = blockIdx.x;
    const int o = tid & 255, kq = tid >> 8;
    float a = 0.f;
    const float* hp = h + b * HH + kq * 128;
    const float* wp = W_fc + (size_t)o * HH + kq * 128;
#pragma unroll 8
    for (int k2 = 0; k2 < 128; ++k2) a += hp[k2] * wp[k2];
    acc[o][kq] = a;
    __syncthreads();
    if (tid < 256) {
        float vv = acc[tid][0] + acc[tid][1] + acc[tid][2] + acc[tid][3] + b_fc[tid];
        out[((size_t)b * TT + (TT - 1)) * OO + tid] = vv;
    }
}

extern "C" void kernel_launch(void* const* d_in, const int* in_sizes, int n_in,
                              void* d_out, int out_size, void* d_ws, size_t ws_size,
                              hipStream_t stream) {
    const float* enc    = (const float*)d_in[0];
    const float* hidden = (const float*)d_in[1];
    const float* cellp  = (const float*)d_in[2];
    const float* target = (const float*)d_in[3];
    const float* W_ih   = (const float*)d_in[4];
    const float* W_hh   = (const float*)d_in[5];
    const float* b_ih   = (const float*)d_in[6];
    const float* b_hh   = (const float*)d_in[7];
    const float* W_fc   = (const float*)d_in[8];
    const float* b_fc   = (const float*)d_in[9];
    float* out = (float*)d_out;

    // R9 ran the ench path => ws_size >= 80,289,792; this layout needs less.
    char* base = (char*)d_ws;
    float* h              = (float*)(base + 0);                  // 131,072 B
    float* c              = (float*)(base + 131072);             // 131,072 B
    unsigned short* wfH   = (unsigned short*)(base + 262144);    // 5,242,880 B
    unsigned short* wfL   = (unsigned short*)(base + 5505024);   // 5,242,880 B
    unsigned short* xbh   = (unsigned short*)(base + 10747904);  // 163,840 B
    unsigned short* xbl   = (unsigned short*)(base + 10911744);  // 163,840 B
    _Float16* ench        = (_Float16*)(base + 11075584);        // 67,108,864 B
    // end: 78,184,448 B

    prep_weights<<<dim3(1280), dim3(256), 0, stream>>>(W_ih, W_hh, wfH, wfL);
    prep_misc<<<dim3(256), dim3(256), 0, stream>>>(hidden, cellp, h, c);
    prep_enc<<<dim3(16384), dim3(256), 0, stream>>>(enc, ench);

    for (int t = 0; t < TT; ++t) {
        step_attnx<<<dim3(128), dim3(1024), 0, stream>>>(
            t, ench, h, target, xbh, xbl, W_fc, b_fc, out);
        step_gates<<<dim3(64), dim3(256), 0, stream>>>(
            xbh, xbl, wfH, wfL, b_ih, b_hh, h, c);
    }
    fc_final<<<dim3(64), dim3(1024), 0, stream>>>(h, W_fc, b_fc, out);
}